// Round 2
// baseline (289.479 us; speedup 1.0000x reference)
//
#include <hip/hip_runtime.h>
#include <hip/hip_cooperative_groups.h>
#include <math.h>

namespace cg = cooperative_groups;

#define BB 16
#define GG 64
#define PP 8400
#define CC 80
#define KK 13
#define SLOTS 12   // ceil(max candidates 691 / 64)
#define NBLK 525   // BB*PP / 256 exactly

__device__ __forceinline__ float iou_calc(float gx1,float gy1,float gx2,float gy2,
                                          float px1,float py1,float px2,float py2){
  float iw = fmaxf(fminf(gx2,px2) - fmaxf(gx1,px1), 0.f);
  float ih = fmaxf(fminf(gy2,py2) - fmaxf(gy1,py1), 0.f);
  float inter = iw*ih;
  float ag = fmaxf(gx2-gx1,0.f)*fmaxf(gy2-gy1,0.f);
  float ap = fmaxf(px2-px1,0.f)*fmaxf(py2-py1,0.f);
  return inter / (ag+ap-inter+1e-9f);
}

// Single cooperative kernel, 525 blocks x 256 threads (= BB*PP threads).
// Phase 0: zero packed counts + per-gt maxima (workspace is re-poisoned
//          between iterations, so this must happen every call).
// Phase 1: per-(b,g) wave top-13 (first 1024 waves), packed atomicAdd marking.
// Phase 2: per-prior resolve; g/m kept in REGISTERS across the sync.
// Phase 3: per-prior output writes; score rows zeroed block-cooperatively
//          (coalesced stripes) then single scatter store per positive.
__launch_bounds__(256, 3)   // cap VGPR so >=3 blocks/CU -> 525 blocks co-resident
__global__ void k_fused(const float* __restrict__ pred_bboxes,
                        const float* __restrict__ pred_scores,
                        const int*   __restrict__ gt_labels,
                        const float* __restrict__ gt_bboxes,
                        const float* __restrict__ pad_flag,
                        int* __restrict__ packed,
                        unsigned int* __restrict__ pos_align,
                        unsigned int* __restrict__ pos_ovl,
                        float* __restrict__ out){
  cg::grid_group grid = cg::this_grid();
  int tid = blockIdx.x*256 + threadIdx.x;   // [0, BB*PP)

  // ---------------- phase 0: zero workspace ----------------
  packed[tid] = 0;
  if (tid < 2*BB*GG){
    if (tid < BB*GG) pos_align[tid] = 0u;
    else             pos_ovl[tid - BB*GG] = 0u;
  }
  grid.sync();

  // ---------------- phase 1: top-k per (b,g) ----------------
  {
    int wv   = tid >> 6;     // global wave id == blockIdx.x*4 + (threadIdx.x>>6)
    int lane = tid & 63;
    if (wv < BB*GG && pad_flag[wv] > 0.f){
      int bg = wv;
      int tb = bg >> 6, tg = bg & 63;
      int lbl = gt_labels[bg];
      float gx1 = gt_bboxes[bg*4+0], gy1 = gt_bboxes[bg*4+1];
      float gx2 = gt_bboxes[bg*4+2], gy2 = gt_bboxes[bg*4+3];

      // rectangle bounds per level (superset; exact dmin check filters below)
      int ixl[3], iyl[3], nx[3], cnt[3];
      const float fs[3] = {8.f,16.f,32.f};
      const int  dim[3] = {80,40,20};
      #pragma unroll
      for (int l=0;l<3;++l){
        float s = fs[l]; int d = dim[l];
        int xlo = max(0,   (int)floorf(gx1/s - 0.5f) - 1);
        int xhi = min(d-1, (int)ceilf (gx2/s - 0.5f) + 1);
        int ylo = max(0,   (int)floorf(gy1/s - 0.5f) - 1);
        int yhi = min(d-1, (int)ceilf (gy2/s - 0.5f) + 1);
        int nxx = xhi-xlo+1; if (nxx < 0) nxx = 0;
        int nyy = yhi-ylo+1; if (nyy < 0) nyy = 0;
        ixl[l]=xlo; iyl[l]=ylo; nx[l]=nxx; cnt[l]=nxx*nyy;
      }
      int Mtot = cnt[0]+cnt[1]+cnt[2];

      const float4* pb4 = (const float4*)(pred_bboxes + (size_t)tb*PP*4);
      const float*  ps  = pred_scores + (size_t)tb*PP*CC + lbl;

      unsigned long long key[SLOTS];
      #pragma unroll
      for (int s=0;s<SLOTS;++s) key[s] = 0ull;

      #pragma unroll
      for (int s=0;s<SLOTS;++s){
        int c = lane + s*64;
        if (c < Mtot){
          int l, rem = c;
          if (rem < cnt[0]) l = 0;
          else { rem -= cnt[0]; if (rem < cnt[1]) l = 1; else { rem -= cnt[1]; l = 2; } }
          int nxl = (l==0)?nx[0]:((l==1)?nx[1]:nx[2]);
          int ix  = ((l==0)?ixl[0]:((l==1)?ixl[1]:ixl[2])) + rem % nxl;
          int iy  = ((l==0)?iyl[0]:((l==1)?iyl[1]:iyl[2])) + rem / nxl;
          float st = (l==0)?8.f:((l==1)?16.f:32.f);
          float px = (ix+0.5f)*st, py = (iy+0.5f)*st;   // bit-exact vs priors array
          float dmin = fminf(fminf(px-gx1, py-gy1), fminf(gx2-px, gy2-py));
          if (dmin > 1e-9f){
            int p = ((l==0)?0:((l==1)?6400:8000)) + iy*((l==0)?80:((l==1)?40:20)) + ix;
            float4 box = pb4[p];
            float ov = iou_calc(gx1,gy1,gx2,gy2, box.x,box.y,box.z,box.w);
            float m = ps[(size_t)p*CC] * powf(ov, 6.0f);
            if (m > 0.f)
              key[s] = ((unsigned long long)__float_as_uint(m) << 32)
                     | (unsigned)(0xFFFFFFFFu - (unsigned)p);
          }
        }
      }

      // 13 rounds of wave-max extraction (exact (m desc, p asc) order)
      int q = 0;
      unsigned long long mywin = 0ull;
      for (int r=0; r<KK; ++r){
        unsigned long long best = 0ull;
        #pragma unroll
        for (int s=0;s<SLOTS;++s) best = (key[s] > best) ? key[s] : best;
        #pragma unroll
        for (int off=32; off>=1; off>>=1){
          unsigned long long o = __shfl_xor(best, off);
          best = (o > best) ? o : best;
        }
        if (best == 0ull) break;
        if (lane == r) mywin = best;
        #pragma unroll
        for (int s=0;s<SLOTS;++s) if (key[s] == best) key[s] = 0ull;
        q++;
      }

      int wp = (lane < q) ? (int)(0xFFFFFFFFu - (unsigned)mywin) : -1;
      int tag = (1 << 24) | (tg + 1);
      if (lane < q){
        atomicAdd(&packed[tb*PP+wp], tag);
      }

      int r13 = KK - q;
      if (r13 > 0){
        // globally smallest-index zeros: p = 0,1,2,... skipping the q winners
        bool isw = false;
        for (int r=0; r<q; ++r) isw |= (lane == __shfl(wp, r));
        unsigned long long zmask = __ballot(!isw);   // bit i: p=i has metric 0
        for (int t=0; t<r13; ++t){
          int p0 = __builtin_ctzll(zmask);
          zmask &= zmask - 1;
          // p0 <= 24 < 80 -> stride-8 row 0: px=(p0+0.5)*8, py=4
          float px = (p0+0.5f)*8.f, py = 4.0f;
          float dmin = fminf(fminf(px-gx1, py-gy1), fminf(gx2-px, gy2-py));
          if (dmin > 1e-9f && lane == 0){
            atomicAdd(&packed[tb*PP+p0], tag);
          }
        }
      }
    }
  }
  grid.sync();

  // ---------------- phase 2: resolve per prior ----------------
  int i = tid;
  int b = i / PP;
  int v = packed[i];
  int c = (unsigned)v >> 24;
  int g = -1;
  float4 box = ((const float4*)pred_bboxes)[i];
  if (c == 1){
    g = (v & 0xFFFFFF) - 1;
  } else if (c > 1){
    // is_max = one_hot(argmax_g overlaps) — ALL g (even padded), first-idx ties
    float best = -1.f; int bgidx = 0;
    const float4* gb4 = (const float4*)(gt_bboxes + (size_t)b*GG*4);
    for (int g2=0; g2<GG; ++g2){
      float4 gb = gb4[g2];
      float ov = iou_calc(gb.x,gb.y,gb.z,gb.w, box.x,box.y,box.z,box.w);
      if (ov > best){ best = ov; bgidx = g2; }
    }
    g = bgidx;
  }
  float m = 0.f;
  if (g >= 0){
    float4 gb = ((const float4*)(gt_bboxes + (size_t)b*GG*4))[g];
    float ov = iou_calc(gb.x,gb.y,gb.z,gb.w, box.x,box.y,box.z,box.w);
    int lbl = gt_labels[b*GG+g];
    float score = pred_scores[(size_t)i*CC + lbl];
    m = score * powf(ov, 6.0f);             // align_metric (no in_gts mask here!)
    atomicMax(&pos_align[b*GG+g], __float_as_uint(m));
    atomicMax(&pos_ovl[b*GG+g], __float_as_uint(ov));
  }
  grid.sync();

  // ---------------- phase 3: outputs ----------------
  float* out_labels = out;
  float* out_bboxes = out + BB*PP;
  float* out_scores = out + (size_t)BB*PP*5;
  float* out_fg     = out + (size_t)BB*PP*5 + (size_t)BB*PP*CC;

  int gi = (g >= 0) ? g : 0;               // argmax of all-zero row -> 0
  int lbl = gt_labels[b*GG+gi]; if (lbl < 0) lbl = 0;

  out_labels[i] = (float)lbl;
  ((float4*)out_bboxes)[i] = ((const float4*)gt_bboxes)[b*GG+gi];
  out_fg[i] = (g >= 0) ? 1.f : 0.f;

  // coalesced zero of this block's contiguous 256-row score stripe
  float4 z; z.x = 0.f; z.y = 0.f; z.z = 0.f; z.w = 0.f;
  float4* stripe = (float4*)(out_scores + (size_t)blockIdx.x*256*CC);
  #pragma unroll
  for (int k2=0; k2<CC/4; ++k2) stripe[k2*256 + threadIdx.x] = z;
  __syncthreads();
  if (g >= 0){
    float pa = __uint_as_float(pos_align[b*GG+g]);
    float po = __uint_as_float(pos_ovl[b*GG+g]);
    out_scores[(size_t)i*CC + lbl] = m * po / (pa + 1e-7f);
  }
}

extern "C" void kernel_launch(void* const* d_in, const int* in_sizes, int n_in,
                              void* d_out, int out_size, void* d_ws, size_t ws_size,
                              hipStream_t stream) {
  const float* pred_bboxes = (const float*)d_in[0];
  const float* pred_scores = (const float*)d_in[1];
  const int*   gt_labels   = (const int*)d_in[3];
  const float* gt_bboxes   = (const float*)d_in[4];
  const float* pad_flag    = (const float*)d_in[5];
  float* out = (float*)d_out;

  int*          packed    = (int*)d_ws;                       // B*P
  unsigned int* pos_align = (unsigned int*)(packed + BB*PP);  // B*G
  unsigned int* pos_ovl   = pos_align + BB*GG;                // B*G

  void* args[] = { (void*)&pred_bboxes, (void*)&pred_scores, (void*)&gt_labels,
                   (void*)&gt_bboxes, (void*)&pad_flag, (void*)&packed,
                   (void*)&pos_align, (void*)&pos_ovl, (void*)&out };
  hipLaunchCooperativeKernel((const void*)k_fused, dim3(NBLK), dim3(256),
                             args, 0, stream);
}

// Round 3
// 156.982 us; speedup vs baseline: 1.8440x; 1.8440x over previous
//
#include <hip/hip_runtime.h>
#include <math.h>

#define BB 16
#define GG 64
#define PP 8400
#define CC 80
#define KK 13
#define SLOTS 3      // ceil(max candidates 691 / 256 threads)
#define LCAP 1664    // per-batch positive-list capacity (max 64 gts * 13)
#define CHUNKS 33    // ceil(8400/256)

__device__ __forceinline__ float iou_calc(float gx1,float gy1,float gx2,float gy2,
                                          float px1,float py1,float px2,float py2){
  float iw = fmaxf(fminf(gx2,px2) - fmaxf(gx1,px1), 0.f);
  float ih = fmaxf(fminf(gy2,py2) - fmaxf(gy1,py1), 0.f);
  float inter = iw*ih;
  float ag = fmaxf(gx2-gx1,0.f)*fmaxf(gy2-gy1,0.f);
  float ap = fmaxf(px2-px1,0.f)*fmaxf(py2-py1,0.f);
  return inter / (ag+ap-inter+1e-9f);
}

// K1: ONE BLOCK per (b,g). Candidates = 3 closed-form grid rectangles (<=691).
// Block-level top-13 by (m desc, p asc) via u64 keys + LDS max-merge rounds.
// Writes dense winners[bg][13] (prior or -1, every slot written -> no memset),
// zeroes pos_align/pos_ovl for its bg and list_n (blocks 0..15).
__launch_bounds__(256)
__global__ void k_topk(const float* __restrict__ pred_bboxes,
                       const float* __restrict__ pred_scores,
                       const int*   __restrict__ gt_labels,
                       const float* __restrict__ gt_bboxes,
                       const float* __restrict__ pad_flag,
                       int* __restrict__ winners,
                       unsigned int* __restrict__ pos_align,
                       unsigned int* __restrict__ pos_ovl,
                       int* __restrict__ list_n){
  int bg  = blockIdx.x;
  int tid = threadIdx.x;
  __shared__ unsigned long long wmax[4];
  __shared__ unsigned long long win[KK];

  if (tid == 0){
    pos_align[bg] = 0u; pos_ovl[bg] = 0u;
    if (bg < BB) list_n[bg] = 0;
  }
  if (pad_flag[bg] <= 0.f){
    if (tid < KK) winners[bg*KK + tid] = -1;   // padded row: no marks
    return;
  }
  int b = bg >> 6;
  int lane = tid & 63, wv = tid >> 6;
  int lbl = gt_labels[bg];
  float gx1 = gt_bboxes[bg*4+0], gy1 = gt_bboxes[bg*4+1];
  float gx2 = gt_bboxes[bg*4+2], gy2 = gt_bboxes[bg*4+3];

  // rectangle bounds per level (superset; exact dmin check filters below)
  int ixl[3], iyl[3], nx[3], cnt[3];
  const float fs[3] = {8.f,16.f,32.f};
  const int  dim[3] = {80,40,20};
  #pragma unroll
  for (int l=0;l<3;++l){
    float s = fs[l]; int d = dim[l];
    int xlo = max(0,   (int)floorf(gx1/s - 0.5f) - 1);
    int xhi = min(d-1, (int)ceilf (gx2/s - 0.5f) + 1);
    int ylo = max(0,   (int)floorf(gy1/s - 0.5f) - 1);
    int yhi = min(d-1, (int)ceilf (gy2/s - 0.5f) + 1);
    int nxx = xhi-xlo+1; if (nxx < 0) nxx = 0;
    int nyy = yhi-ylo+1; if (nyy < 0) nyy = 0;
    ixl[l]=xlo; iyl[l]=ylo; nx[l]=nxx; cnt[l]=nxx*nyy;
  }
  int Mtot = cnt[0]+cnt[1]+cnt[2];

  const float4* pb4 = (const float4*)(pred_bboxes + (size_t)b*PP*4);
  const float*  ps  = pred_scores + (size_t)b*PP*CC + lbl;

  unsigned long long key[SLOTS];
  #pragma unroll
  for (int s=0;s<SLOTS;++s) key[s] = 0ull;

  #pragma unroll
  for (int s=0;s<SLOTS;++s){
    int c = tid + s*256;
    if (c < Mtot){
      int l, rem = c;
      if (rem < cnt[0]) l = 0;
      else { rem -= cnt[0]; if (rem < cnt[1]) l = 1; else { rem -= cnt[1]; l = 2; } }
      int nxl = (l==0)?nx[0]:((l==1)?nx[1]:nx[2]);
      int ix  = ((l==0)?ixl[0]:((l==1)?ixl[1]:ixl[2])) + rem % nxl;
      int iy  = ((l==0)?iyl[0]:((l==1)?iyl[1]:iyl[2])) + rem / nxl;
      float st = (l==0)?8.f:((l==1)?16.f:32.f);
      float px = (ix+0.5f)*st, py = (iy+0.5f)*st;   // bit-exact vs priors array
      float dmin = fminf(fminf(px-gx1, py-gy1), fminf(gx2-px, gy2-py));
      if (dmin > 1e-9f){
        int p = ((l==0)?0:((l==1)?6400:8000)) + iy*((l==0)?80:((l==1)?40:20)) + ix;
        float4 box = pb4[p];
        float ov = iou_calc(gx1,gy1,gx2,gy2, box.x,box.y,box.z,box.w);
        float m = ps[(size_t)p*CC] * powf(ov, 6.0f);
        if (m > 0.f)
          key[s] = ((unsigned long long)__float_as_uint(m) << 32)
                 | (unsigned)(0xFFFFFFFFu - (unsigned)p);
      }
    }
  }

  // 13 rounds of block-max extraction (exact (m desc, p asc) order)
  int q = 0;
  for (int r=0; r<KK; ++r){
    unsigned long long best = key[0];
    #pragma unroll
    for (int s=1;s<SLOTS;++s) best = (key[s] > best) ? key[s] : best;
    #pragma unroll
    for (int off=32; off>=1; off>>=1){
      unsigned long long o = __shfl_xor(best, off);
      best = (o > best) ? o : best;
    }
    if (lane == 0) wmax[wv] = best;
    __syncthreads();
    unsigned long long bb = wmax[0];
    bb = (wmax[1] > bb) ? wmax[1] : bb;
    bb = (wmax[2] > bb) ? wmax[2] : bb;
    bb = (wmax[3] > bb) ? wmax[3] : bb;
    if (bb == 0ull) break;               // uniform across block
    if (tid == 0) win[r] = bb;
    #pragma unroll
    for (int s=0;s<SLOTS;++s) if (key[s] == bb) key[s] = 0ull;
    q++;
    __syncthreads();
  }
  __syncthreads();

  if (tid < q)
    winners[bg*KK + tid] = (int)(0xFFFFFFFFu - (unsigned)win[tid]);

  if (tid == 0 && q < KK){
    // remaining slots: globally smallest-index zero-metric priors, skipping
    // winners (q<13 => every positive-metric prior IS a winner). Mark only
    // if in-box (is_in_gts re-mask); slot consumed either way.
    int p0 = 0;
    for (int t=q; t<KK; ++t){
      for (;;){
        bool isw = false;
        for (int r2=0; r2<q; ++r2)
          if ((int)(0xFFFFFFFFu - (unsigned)win[r2]) == p0){ isw = true; break; }
        if (!isw) break;
        ++p0;
      }
      // p0 <= 25 < 80 -> stride-8 row 0: px=(p0+0.5)*8, py=4
      float px = (p0+0.5f)*8.f, py = 4.0f;
      float dmin = fminf(fminf(px-gx1, py-gy1), fminf(gx2-px, gy2-py));
      winners[bg*KK + t] = (dmin > 1e-9f) ? p0 : -1;
      ++p0;
    }
  }
}

// K2: per prior. Blocks aligned to batches (16 x 33 chunks of 256 priors).
// Loads batch-b winners (64*13) into LDS, scans for count+gt, resolves
// multi-assignment, writes labels/bboxes/fg, zeroes score stripe coalesced,
// appends positives to per-batch list, atomicMax per-gt maxima.
__launch_bounds__(256)
__global__ void k_resolve(const float* __restrict__ pred_bboxes,
                          const float* __restrict__ pred_scores,
                          const int*   __restrict__ gt_labels,
                          const float* __restrict__ gt_bboxes,
                          const int*   __restrict__ winners,
                          unsigned int* __restrict__ pos_align,
                          unsigned int* __restrict__ pos_ovl,
                          int* __restrict__ list_n,
                          int4* __restrict__ list,
                          float* __restrict__ out){
  int blk = blockIdx.x;
  int b = blk / CHUNKS, ch = blk % CHUNKS;
  int tid = threadIdx.x;
  __shared__ int wl[GG*KK];
  for (int j=tid; j<GG*KK; j+=256) wl[j] = winners[b*GG*KK + j];

  float* out_labels = out;
  float* out_bboxes = out + BB*PP;
  float* out_scores = out + (size_t)BB*PP*5;
  float* out_fg     = out + (size_t)BB*PP*5 + (size_t)BB*PP*CC;

  // coalesced zero of this chunk's score stripe
  int row0 = ch*256;
  int nrows = PP - row0; if (nrows > 256) nrows = 256;
  float4 z; z.x=0.f; z.y=0.f; z.z=0.f; z.w=0.f;
  float4* stripe = (float4*)(out_scores + ((size_t)b*PP + row0)*CC);
  int n4 = nrows*CC/4;
  for (int t=tid; t<n4; t+=256) stripe[t] = z;
  __syncthreads();

  int p = row0 + tid;
  if (p >= PP) return;
  int i = b*PP + p;

  // scan winner lists: count of claiming gts + (unique) claimant
  int cnt2 = 0, gsel = 0;
  for (int gg2=0; gg2<GG; ++gg2){
    #pragma unroll
    for (int s=0; s<KK; ++s){
      if (wl[gg2*KK+s] == p){ cnt2++; gsel = gg2; }
    }
  }

  float4 box = ((const float4*)pred_bboxes)[i];
  int g = -1;
  if (cnt2 == 1){
    g = gsel;
  } else if (cnt2 > 1){
    // is_max = one_hot(argmax_g overlaps) — ALL g (even padded), first-idx ties
    float best = -1.f; int bgidx = 0;
    const float4* gb4 = (const float4*)(gt_bboxes + (size_t)b*GG*4);
    for (int g2=0; g2<GG; ++g2){
      float4 gb = gb4[g2];
      float ov = iou_calc(gb.x,gb.y,gb.z,gb.w, box.x,box.y,box.z,box.w);
      if (ov > best){ best = ov; bgidx = g2; }
    }
    g = bgidx;
  }

  int gi = (g >= 0) ? g : 0;               // argmax of all-zero row -> 0
  int lbl = gt_labels[b*GG+gi]; if (lbl < 0) lbl = 0;
  out_labels[i] = (float)lbl;
  ((float4*)out_bboxes)[i] = ((const float4*)gt_bboxes)[b*GG+gi];
  out_fg[i] = (g >= 0) ? 1.f : 0.f;

  if (g >= 0){
    float4 gb = ((const float4*)(gt_bboxes + (size_t)b*GG*4))[g];
    float ov = iou_calc(gb.x,gb.y,gb.z,gb.w, box.x,box.y,box.z,box.w);
    float score = pred_scores[(size_t)i*CC + lbl];
    float m = score * powf(ov, 6.0f);      // align_metric (no in_gts mask here!)
    atomicMax(&pos_align[b*GG+g], __float_as_uint(m));
    atomicMax(&pos_ovl[b*GG+g], __float_as_uint(ov));
    int slot = atomicAdd(&list_n[b], 1);
    int4 e; e.x = i; e.y = b*GG+g; e.z = __float_as_int(m); e.w = 0;
    list[b*LCAP + slot] = e;
  }
}

// K3: tiny — one block per batch walks the positive list and writes the
// single normalized score per positive (per-gt maxima now final).
__launch_bounds__(256)
__global__ void k_norm(const int* __restrict__ gt_labels,
                       const unsigned int* __restrict__ pos_align,
                       const unsigned int* __restrict__ pos_ovl,
                       const int* __restrict__ list_n,
                       const int4* __restrict__ list,
                       float* __restrict__ out){
  int b = blockIdx.x;
  int n = list_n[b];
  float* out_scores = out + (size_t)BB*PP*5;
  for (int t=threadIdx.x; t<n; t+=256){
    int4 e = list[b*LCAP + t];
    int i = e.x, bg = e.y;
    float m = __int_as_float(e.z);
    float pa = __uint_as_float(pos_align[bg]);
    float po = __uint_as_float(pos_ovl[bg]);
    int lbl = gt_labels[bg]; if (lbl < 0) lbl = 0;
    out_scores[(size_t)i*CC + lbl] = m * po / (pa + 1e-7f);
  }
}

extern "C" void kernel_launch(void* const* d_in, const int* in_sizes, int n_in,
                              void* d_out, int out_size, void* d_ws, size_t ws_size,
                              hipStream_t stream) {
  const float* pred_bboxes = (const float*)d_in[0];
  const float* pred_scores = (const float*)d_in[1];
  const int*   gt_labels   = (const int*)d_in[3];
  const float* gt_bboxes   = (const float*)d_in[4];
  const float* pad_flag    = (const float*)d_in[5];
  float* out = (float*)d_out;

  int*          winners   = (int*)d_ws;                        // B*G*13
  unsigned int* pos_align = (unsigned int*)(winners + BB*GG*KK); // B*G
  unsigned int* pos_ovl   = pos_align + BB*GG;                   // B*G
  int*          list_n    = (int*)(pos_ovl + BB*GG);             // B
  int4*         list      = (int4*)(list_n + 64);                // B*LCAP (aligned)

  k_topk<<<BB*GG, 256, 0, stream>>>(pred_bboxes, pred_scores, gt_labels,
                                    gt_bboxes, pad_flag, winners,
                                    pos_align, pos_ovl, list_n);
  k_resolve<<<BB*CHUNKS, 256, 0, stream>>>(pred_bboxes, pred_scores, gt_labels,
                                           gt_bboxes, winners, pos_align, pos_ovl,
                                           list_n, list, out);
  k_norm<<<BB, 256, 0, stream>>>(gt_labels, pos_align, pos_ovl, list_n, list, out);
}

// Round 5
// 149.044 us; speedup vs baseline: 1.9422x; 1.0533x over previous
//
#include <hip/hip_runtime.h>
#include <math.h>

#define BB 16
#define GG 64
#define PP 8400
#define CC 80
#define KK 13
#define SLOTS 3      // ceil(max candidates 691 / 256 threads)
#define LCAP 1664    // per-batch positive-list capacity (max 64 gts * 13)
#define CH 128       // rows per k_resolve block
#define NCH 66       // ceil(8400/128)

__device__ __forceinline__ float iou_calc(float gx1,float gy1,float gx2,float gy2,
                                          float px1,float py1,float px2,float py2){
  float iw = fmaxf(fminf(gx2,px2) - fmaxf(gx1,px1), 0.f);
  float ih = fmaxf(fminf(gy2,py2) - fmaxf(gy1,py1), 0.f);
  float inter = iw*ih;
  float ag = fmaxf(gx2-gx1,0.f)*fmaxf(gy2-gy1,0.f);
  float ap = fmaxf(px2-px1,0.f)*fmaxf(py2-py1,0.f);
  return inter / (ag+ap-inter+1e-9f);
}

// K1: ONE BLOCK per (b,g). Candidates = 3 closed-form grid rectangles (<=691).
// Block-level top-13 by (m desc, p asc) via u64 keys + LDS max-merge rounds.
// Writes dense winners[bg][13] (prior or -1, every slot written -> no memset),
// zeroes pos_align/pos_ovl for its bg and list_n (blocks 0..15).
__launch_bounds__(256)
__global__ void k_topk(const float* __restrict__ pred_bboxes,
                       const float* __restrict__ pred_scores,
                       const int*   __restrict__ gt_labels,
                       const float* __restrict__ gt_bboxes,
                       const float* __restrict__ pad_flag,
                       int* __restrict__ winners,
                       unsigned int* __restrict__ pos_align,
                       unsigned int* __restrict__ pos_ovl,
                       int* __restrict__ list_n){
  int bg  = blockIdx.x;
  int tid = threadIdx.x;
  __shared__ unsigned long long wmax[4];
  __shared__ unsigned long long win[KK];

  if (tid == 0){
    pos_align[bg] = 0u; pos_ovl[bg] = 0u;
    if (bg < BB) list_n[bg] = 0;
  }
  if (pad_flag[bg] <= 0.f){
    if (tid < KK) winners[bg*KK + tid] = -1;   // padded row: no marks
    return;
  }
  int b = bg >> 6;
  int lane = tid & 63, wv = tid >> 6;
  int lbl = gt_labels[bg];
  float gx1 = gt_bboxes[bg*4+0], gy1 = gt_bboxes[bg*4+1];
  float gx2 = gt_bboxes[bg*4+2], gy2 = gt_bboxes[bg*4+3];

  // rectangle bounds per level (superset; exact dmin check filters below)
  int ixl[3], iyl[3], nx[3], cnt[3];
  const float fs[3] = {8.f,16.f,32.f};
  const int  dim[3] = {80,40,20};
  #pragma unroll
  for (int l=0;l<3;++l){
    float s = fs[l]; int d = dim[l];
    int xlo = max(0,   (int)floorf(gx1/s - 0.5f) - 1);
    int xhi = min(d-1, (int)ceilf (gx2/s - 0.5f) + 1);
    int ylo = max(0,   (int)floorf(gy1/s - 0.5f) - 1);
    int yhi = min(d-1, (int)ceilf (gy2/s - 0.5f) + 1);
    int nxx = xhi-xlo+1; if (nxx < 0) nxx = 0;
    int nyy = yhi-ylo+1; if (nyy < 0) nyy = 0;
    ixl[l]=xlo; iyl[l]=ylo; nx[l]=nxx; cnt[l]=nxx*nyy;
  }
  int Mtot = cnt[0]+cnt[1]+cnt[2];

  const float4* pb4 = (const float4*)(pred_bboxes + (size_t)b*PP*4);
  const float*  ps  = pred_scores + (size_t)b*PP*CC + lbl;

  unsigned long long key[SLOTS];
  #pragma unroll
  for (int s=0;s<SLOTS;++s) key[s] = 0ull;

  #pragma unroll
  for (int s=0;s<SLOTS;++s){
    int c = tid + s*256;
    if (c < Mtot){
      int l, rem = c;
      if (rem < cnt[0]) l = 0;
      else { rem -= cnt[0]; if (rem < cnt[1]) l = 1; else { rem -= cnt[1]; l = 2; } }
      int nxl = (l==0)?nx[0]:((l==1)?nx[1]:nx[2]);
      int ix  = ((l==0)?ixl[0]:((l==1)?ixl[1]:ixl[2])) + rem % nxl;
      int iy  = ((l==0)?iyl[0]:((l==1)?iyl[1]:iyl[2])) + rem / nxl;
      float st = (l==0)?8.f:((l==1)?16.f:32.f);
      float px = (ix+0.5f)*st, py = (iy+0.5f)*st;   // bit-exact vs priors array
      float dmin = fminf(fminf(px-gx1, py-gy1), fminf(gx2-px, gy2-py));
      if (dmin > 1e-9f){
        int p = ((l==0)?0:((l==1)?6400:8000)) + iy*((l==0)?80:((l==1)?40:20)) + ix;
        float4 box = pb4[p];
        float ov = iou_calc(gx1,gy1,gx2,gy2, box.x,box.y,box.z,box.w);
        float m = ps[(size_t)p*CC] * powf(ov, 6.0f);
        if (m > 0.f)
          key[s] = ((unsigned long long)__float_as_uint(m) << 32)
                 | (unsigned)(0xFFFFFFFFu - (unsigned)p);
      }
    }
  }

  // 13 rounds of block-max extraction (exact (m desc, p asc) order)
  int q = 0;
  for (int r=0; r<KK; ++r){
    unsigned long long best = key[0];
    #pragma unroll
    for (int s=1;s<SLOTS;++s) best = (key[s] > best) ? key[s] : best;
    #pragma unroll
    for (int off=32; off>=1; off>>=1){
      unsigned long long o = __shfl_xor(best, off);
      best = (o > best) ? o : best;
    }
    if (lane == 0) wmax[wv] = best;
    __syncthreads();
    unsigned long long bb = wmax[0];
    bb = (wmax[1] > bb) ? wmax[1] : bb;
    bb = (wmax[2] > bb) ? wmax[2] : bb;
    bb = (wmax[3] > bb) ? wmax[3] : bb;
    if (bb == 0ull) break;               // uniform across block
    if (tid == 0) win[r] = bb;
    #pragma unroll
    for (int s=0;s<SLOTS;++s) if (key[s] == bb) key[s] = 0ull;
    q++;
    __syncthreads();
  }
  __syncthreads();

  if (tid < q)
    winners[bg*KK + tid] = (int)(0xFFFFFFFFu - (unsigned)win[tid]);

  if (tid == 0 && q < KK){
    // remaining slots: globally smallest-index zero-metric priors, skipping
    // winners (q<13 => every positive-metric prior IS a winner). Mark only
    // if in-box (is_in_gts re-mask); slot consumed either way.
    int p0 = 0;
    for (int t=q; t<KK; ++t){
      for (;;){
        bool isw = false;
        for (int r2=0; r2<q; ++r2)
          if ((int)(0xFFFFFFFFu - (unsigned)win[r2]) == p0){ isw = true; break; }
        if (!isw) break;
        ++p0;
      }
      // p0 <= 25 < 80 -> stride-8 row 0: px=(p0+0.5)*8, py=4
      float px = (p0+0.5f)*8.f, py = 4.0f;
      float dmin = fminf(fminf(px-gx1, py-gy1), fminf(gx2-px, gy2-py));
      winners[bg*KK + t] = (dmin > 1e-9f) ? p0 : -1;
      ++p0;
    }
  }
}

// K2: per prior, INVERTED marking. One block per 128-row chunk (16 x 66).
// Winners of this batch (832 ints) are streamed coalesced; each winner landing
// in this chunk marks LDS mark[rel] += (1<<16)|(g+1). Each prior then reads
// its own count/g in O(1). Score stripe zeroed coalesced. Positives appended
// to per-batch list; per-gt maxima via atomicMax.
__launch_bounds__(256)
__global__ void k_resolve(const float* __restrict__ pred_bboxes,
                          const float* __restrict__ pred_scores,
                          const int*   __restrict__ gt_labels,
                          const float* __restrict__ gt_bboxes,
                          const int*   __restrict__ winners,
                          unsigned int* __restrict__ pos_align,
                          unsigned int* __restrict__ pos_ovl,
                          int* __restrict__ list_n,
                          int4* __restrict__ list,
                          float* __restrict__ out){
  int blk = blockIdx.x;
  int b = blk / NCH, ch = blk % NCH;
  int row0 = ch*CH;
  int nrows = PP - row0; if (nrows > CH) nrows = CH;
  int tid = threadIdx.x;
  __shared__ int mark[CH];
  if (tid < CH) mark[tid] = 0;
  __syncthreads();

  // invert: winners mark their prior (<=4 coalesced reads/thread, rare atomics)
  for (int j=tid; j<GG*KK; j+=256){
    int p = winners[b*GG*KK + j];
    int rel = p - row0;
    if (p >= 0 && rel >= 0 && rel < nrows){
      int g = j / KK;
      atomicAdd(&mark[rel], (1<<16) | (g+1));
    }
  }

  float* out_labels = out;
  float* out_bboxes = out + BB*PP;
  float* out_scores = out + (size_t)BB*PP*5;
  float* out_fg     = out + (size_t)BB*PP*5 + (size_t)BB*PP*CC;

  // coalesced zero of this chunk's score stripe (overlaps mark-atomic latency)
  float4 z; z.x=0.f; z.y=0.f; z.z=0.f; z.w=0.f;
  float4* stripe = (float4*)(out_scores + ((size_t)b*PP + row0)*CC);
  int n4 = nrows*CC/4;
  for (int t=tid; t<n4; t+=256) stripe[t] = z;
  __syncthreads();

  if (tid >= nrows) return;
  int p = row0 + tid;
  int i = b*PP + p;

  int v = mark[tid];
  int cnt2 = (unsigned)v >> 16;
  int g = -1;
  if (cnt2 == 1){
    g = (v & 0xFFFF) - 1;
  } else if (cnt2 > 1){
    // is_max = one_hot(argmax_g overlaps) — ALL g (even padded), first-idx ties
    float4 box = ((const float4*)pred_bboxes)[i];
    float best = -1.f; int bgidx = 0;
    const float4* gb4 = (const float4*)(gt_bboxes + (size_t)b*GG*4);
    for (int g2=0; g2<GG; ++g2){
      float4 gb = gb4[g2];
      float ov = iou_calc(gb.x,gb.y,gb.z,gb.w, box.x,box.y,box.z,box.w);
      if (ov > best){ best = ov; bgidx = g2; }
    }
    g = bgidx;
  }

  int gi = (g >= 0) ? g : 0;               // argmax of all-zero row -> 0
  int lbl = gt_labels[b*GG+gi]; if (lbl < 0) lbl = 0;
  out_labels[i] = (float)lbl;
  ((float4*)out_bboxes)[i] = ((const float4*)gt_bboxes)[b*GG+gi];
  out_fg[i] = (g >= 0) ? 1.f : 0.f;

  if (g >= 0){
    float4 box = ((const float4*)pred_bboxes)[i];
    float4 gb = ((const float4*)(gt_bboxes + (size_t)b*GG*4))[g];
    float ov = iou_calc(gb.x,gb.y,gb.z,gb.w, box.x,box.y,box.z,box.w);
    float score = pred_scores[(size_t)i*CC + lbl];
    float m = score * powf(ov, 6.0f);      // align_metric (no in_gts mask here!)
    atomicMax(&pos_align[b*GG+g], __float_as_uint(m));
    atomicMax(&pos_ovl[b*GG+g], __float_as_uint(ov));
    int slot = atomicAdd(&list_n[b], 1);
    int4 e; e.x = i; e.y = b*GG+g; e.z = __float_as_int(m); e.w = 0;
    list[b*LCAP + slot] = e;
  }
}

// K3: tiny — one block per batch walks the positive list and writes the
// single normalized score per positive (per-gt maxima now final).
__launch_bounds__(256)
__global__ void k_norm(const int* __restrict__ gt_labels,
                       const unsigned int* __restrict__ pos_align,
                       const unsigned int* __restrict__ pos_ovl,
                       const int* __restrict__ list_n,
                       const int4* __restrict__ list,
                       float* __restrict__ out){
  int b = blockIdx.x;
  int n = list_n[b];
  float* out_scores = out + (size_t)BB*PP*5;
  for (int t=threadIdx.x; t<n; t+=256){
    int4 e = list[b*LCAP + t];
    int i = e.x, bg = e.y;
    float m = __int_as_float(e.z);
    float pa = __uint_as_float(pos_align[bg]);
    float po = __uint_as_float(pos_ovl[bg]);
    int lbl = gt_labels[bg]; if (lbl < 0) lbl = 0;
    out_scores[(size_t)i*CC + lbl] = m * po / (pa + 1e-7f);
  }
}

extern "C" void kernel_launch(void* const* d_in, const int* in_sizes, int n_in,
                              void* d_out, int out_size, void* d_ws, size_t ws_size,
                              hipStream_t stream) {
  const float* pred_bboxes = (const float*)d_in[0];
  const float* pred_scores = (const float*)d_in[1];
  const int*   gt_labels   = (const int*)d_in[3];
  const float* gt_bboxes   = (const float*)d_in[4];
  const float* pad_flag    = (const float*)d_in[5];
  float* out = (float*)d_out;

  int*          winners   = (int*)d_ws;                          // B*G*13
  unsigned int* pos_align = (unsigned int*)(winners + BB*GG*KK); // B*G
  unsigned int* pos_ovl   = pos_align + BB*GG;                   // B*G
  int*          list_n    = (int*)(pos_ovl + BB*GG);             // B
  int4*         list      = (int4*)(list_n + 64);                // B*LCAP (aligned)

  k_topk<<<BB*GG, 256, 0, stream>>>(pred_bboxes, pred_scores, gt_labels,
                                    gt_bboxes, pad_flag, winners,
                                    pos_align, pos_ovl, list_n);
  k_resolve<<<BB*NCH, 256, 0, stream>>>(pred_bboxes, pred_scores, gt_labels,
                                        gt_bboxes, winners, pos_align, pos_ovl,
                                        list_n, list, out);
  k_norm<<<BB, 256, 0, stream>>>(gt_labels, pos_align, pos_ovl, list_n, list, out);
}